// Round 7
// baseline (1285.462 us; speedup 1.0000x reference)
//
#include <hip/hip_runtime.h>
#include <cstdint>

// Problem constants
constexpr int Cc = 95;    // input channels
constexpr int Hh = 128;   // hidden
constexpr int G  = 512;   // 4*H gates
constexpr int Bb = 256;   // batch
constexpr int Tt = 1000;  // timesteps
#define EPSBN 1e-5f

typedef _Float16 half8  __attribute__((ext_vector_type(8)));
typedef float floatx4 __attribute__((ext_vector_type(4)));
typedef float float4u __attribute__((ext_vector_type(4), aligned(4)));
typedef float float2u __attribute__((ext_vector_type(2), aligned(4)));

__device__ __forceinline__ unsigned pku(float a, float b) {
  return __builtin_bit_cast(unsigned, __builtin_amdgcn_cvt_pkrtz(a, b));
}
__device__ __forceinline__ float fsigm(float y) {
  y = fminf(30.f, fmaxf(-30.f, y));
  float e = __expf(-y);
  return __fdividef(1.f, 1.f + e);
}
__device__ __forceinline__ float ftanh2(float x) {  // tanh via exp(2x)
  float y = fminf(30.f, fmaxf(-30.f, 2.f * x));
  float e = __expf(y);
  return __fdividef(e - 1.f, e + 1.f);
}

// ---------------------------------------------------------------------------
// K0 (once per launch): fold BN into W_ih -> Wp f16 [512][96] (k=95 padded 0),
// bias'[g] = b_ih+b_hh + sum_c sft_c * W_ih[g][c].
// ---------------------------------------------------------------------------
__global__ __launch_bounds__(512)
void k0_prep(const float* __restrict__ gamma, const float* __restrict__ beta,
             const float* __restrict__ rmean, const float* __restrict__ rvar,
             const float* __restrict__ W_ih, const float* __restrict__ b_ih,
             const float* __restrict__ b_hh, float* __restrict__ biasp,
             _Float16* __restrict__ Wp) {
  __shared__ float scl[Cc], sft[Cc];
  const int t = threadIdx.x;
  if (t < Cc) {
    float s = gamma[t] * rsqrtf(rvar[t] + EPSBN);
    scl[t] = s;
    sft[t] = beta[t] - rmean[t] * s;
  }
  __syncthreads();
  float acc = b_ih[t] + b_hh[t];
  const float* wr = W_ih + (size_t)t * Cc;
  for (int c = 0; c < Cc; ++c) {
    float w = wr[c];
    acc = fmaf(sft[c], w, acc);
    Wp[t * 96 + c] = (_Float16)(w * scl[c]);  // RNE cast
  }
  Wp[t * 96 + 95] = (_Float16)0.f;
  biasp[t] = acc;
}

// ---------------------------------------------------------------------------
// K1: xwT[m][j][q] = (x_f16 . Wp^T + bias') transposed-gate layout so K2 can
// fetch a unit's 4 gate biases with one dwordx4. mfma_f32_16x16x32_f16.
// ---------------------------------------------------------------------------
template <int TC>
__global__ __launch_bounds__(512)
void k1_mfma(const float* __restrict__ x, const _Float16* __restrict__ Wp,
             const float* __restrict__ biasp, float* __restrict__ xwT, int t0) {
  const int tid = threadIdx.x;
  const int wave = tid >> 6, lane = tid & 63;
  const int wm = wave >> 2, wn = wave & 3;
  const int row0 = blockIdx.x * 64 + wm * 32;
  const int nb0 = wn * 128;
  const int l15 = lane & 15, lg = lane >> 4;

  uint4 afr[2][3];
#pragma unroll
  for (int mt = 0; mt < 2; ++mt) {
    int m = row0 + mt * 16 + l15;
    int b = m / TC, tl = m - b * TC;
    const float* xr = x + ((size_t)b * Tt + t0 + tl) * Cc;
#pragma unroll
    for (int kk = 0; kk < 3; ++kk) {
      int k = kk * 32 + lg * 8;
      float4u p0 = *reinterpret_cast<const float4u*>(xr + k);
      float e4, e5, e6, e7;
      if (k == 88) {
        float2u q = *reinterpret_cast<const float2u*>(xr + 92);
        e4 = q[0]; e5 = q[1]; e6 = xr[94]; e7 = 0.f;
      } else {
        float4u p1 = *reinterpret_cast<const float4u*>(xr + k + 4);
        e4 = p1[0]; e5 = p1[1]; e6 = p1[2]; e7 = p1[3];
      }
      afr[mt][kk] = make_uint4(pku(p0[0], p0[1]), pku(p0[2], p0[3]),
                               pku(e4, e5), pku(e6, e7));
    }
  }

  floatx4 acc[2][8] = {};
#pragma unroll
  for (int nt = 0; nt < 8; ++nt) {
    const _Float16* wrow = Wp + (size_t)(nb0 + nt * 16 + l15) * 96 + lg * 8;
#pragma unroll
    for (int kk = 0; kk < 3; ++kk) {
      uint4 bfr = *reinterpret_cast<const uint4*>(wrow + kk * 32);
      half8 bv = __builtin_bit_cast(half8, bfr);
      acc[0][nt] = __builtin_amdgcn_mfma_f32_16x16x32_f16(
          __builtin_bit_cast(half8, afr[0][kk]), bv, acc[0][nt], 0, 0, 0);
      acc[1][nt] = __builtin_amdgcn_mfma_f32_16x16x32_f16(
          __builtin_bit_cast(half8, afr[1][kk]), bv, acc[1][nt], 0, 0, 0);
    }
  }

#pragma unroll
  for (int nt = 0; nt < 8; ++nt) {
    int n = nb0 + nt * 16 + l15;
    int j = n & 127, q = n >> 7;
    float bias = biasp[n];
#pragma unroll
    for (int mt = 0; mt < 2; ++mt) {
      int rbase = row0 + mt * 16 + lg * 4;
#pragma unroll
      for (int r = 0; r < 4; ++r)
        xwT[(size_t)(rbase + r) * G + j * 4 + q] = acc[mt][nt][r] + bias;
    }
  }
}

// ---------------------------------------------------------------------------
// K2: LSTM recurrence via MFMA, TWO batch elements per block (512 thr, 8
// waves; waves 0-3 batch A -> SIMDs 0-3, waves 4-7 batch B -> same SIMDs:
// two independent latency chains interleave per SIMD).
// Wave w' = wave&3 owns units [32w', 32w'+32): A-frags = W_hh rows (f16,
// 128 VGPR). Per step:
//   4x ds_read_b128 of f16 h -> B-frags (B[k][n]=h[k] for all n)
//   32 MFMA -> EVERY lane holds gates of 8 units (D cols identical)
//   in-register extraction (cndmask tree, no LDS round-trip):
//     unit u = 32w' + 16(l15&1) + 4lg + ((l15>>1)&3), gates = acc[2q+hh][rr]
//   xw biases: ONE dwordx4 from xwT (prefetched 2 deep)
//   activations -> c,h; owners (l15<8) write h f16 -> LDS; ONE barrier.
// ---------------------------------------------------------------------------
template <int TC>
__global__ __launch_bounds__(512, 2)
void k2_lstm(const float* __restrict__ xwT, const float* __restrict__ W_hh,
             float* __restrict__ hstate, float* __restrict__ cstate,
             const float* __restrict__ fc_w, const float* __restrict__ fc_b,
             float* __restrict__ out, int t0) {
  __shared__ __align__(16) _Float16 h2[2][2][Hh];  // [sub][buf][unit]
  __shared__ float h32[2][Hh];

  const int tid = threadIdx.x;
  const int wave = tid >> 6;
  const int sub = wave >> 2;           // batch selector within block
  const int w = wave & 3;              // unit group
  const int lane = tid & 63;
  const int l15 = lane & 15, lg = lane >> 4;
  const int hh = l15 & 1, rr = (l15 >> 1) & 3;  // l15>=8 duplicates l15-8
  const int u = 32 * w + 16 * hh + 4 * lg + rr; // unit this lane updates
  const int b = blockIdx.x * 2 + sub;
  const bool owner = (l15 < 8);

  // A-fragments: W_hh rows (f16) 8 tiles x 4 k-chunks -> 128 VGPRs
  uint4 afr[8][4];
#pragma unroll
  for (int q = 0; q < 4; ++q)
#pragma unroll
    for (int h2i = 0; h2i < 2; ++h2i) {
      const float* wr =
          W_hh + (size_t)(q * 128 + 32 * w + 16 * h2i + l15) * Hh + 8 * lg;
#pragma unroll
      for (int kc = 0; kc < 4; ++kc) {
        float4u p0 = *reinterpret_cast<const float4u*>(wr + 32 * kc);
        float4u p1 = *reinterpret_cast<const float4u*>(wr + 32 * kc + 4);
        afr[2 * q + h2i][kc] = make_uint4(pku(p0[0], p0[1]), pku(p0[2], p0[3]),
                                          pku(p1[0], p1[1]), pku(p1[2], p1[3]));
      }
    }

  float creg = 0.f, hreg = 0.f;
  if (t0 == 0) {
    if (owner) h2[sub][0][u] = (_Float16)0.f;
  } else {
    creg = cstate[b * Hh + u];
    hreg = hstate[b * Hh + u];
    if (owner) h2[sub][0][u] = (_Float16)hreg;
  }
  __syncthreads();

  const float* xb = xwT + (size_t)b * TC * G + 4 * u;
  float4u cur = *reinterpret_cast<const float4u*>(xb);
  float4u nxt = {0.f, 0.f, 0.f, 0.f};
  if (TC > 1) nxt = *reinterpret_cast<const float4u*>(xb + G);

  for (int tl = 0; tl < TC; ++tl) {
    const int rb = tl & 1;
    float4u pre = {0.f, 0.f, 0.f, 0.f};
    if (tl + 2 < TC)
      pre = *reinterpret_cast<const float4u*>(xb + (size_t)(tl + 2) * G);

    // B-fragments from f16 h (address depends on lg only -> broadcast)
    uint4 bfr[4];
#pragma unroll
    for (int kc = 0; kc < 4; ++kc)
      bfr[kc] = *reinterpret_cast<const uint4*>(&h2[sub][rb][32 * kc + 8 * lg]);

    floatx4 acc[8] = {};
#pragma unroll
    for (int t = 0; t < 8; ++t)
#pragma unroll
      for (int kc = 0; kc < 4; ++kc)
        acc[t] = __builtin_amdgcn_mfma_f32_16x16x32_f16(
            __builtin_bit_cast(half8, afr[t][kc]),
            __builtin_bit_cast(half8, bfr[kc]), acc[t], 0, 0, 0);

    // in-register gate extraction (all indices compile-time)
    float gq[4];
#pragma unroll
    for (int q = 0; q < 4; ++q) {
      float e0 = hh ? acc[2 * q + 1][0] : acc[2 * q][0];
      float e1 = hh ? acc[2 * q + 1][1] : acc[2 * q][1];
      float e2 = hh ? acc[2 * q + 1][2] : acc[2 * q][2];
      float e3 = hh ? acc[2 * q + 1][3] : acc[2 * q][3];
      float lo = (rr & 1) ? e1 : e0;
      float hi = (rr & 1) ? e3 : e2;
      gq[q] = (rr & 2) ? hi : lo;
    }

    float i_ = fsigm(gq[0] + cur[0]);
    float f_ = fsigm(gq[1] + cur[1]);
    float g_ = ftanh2(gq[2] + cur[2]);
    float o_ = fsigm(gq[3] + cur[3]);

    creg = fmaf(f_, creg, i_ * g_);
    hreg = o_ * ftanh2(creg);

    if (owner) h2[sub][rb ^ 1][u] = (_Float16)hreg;
    __syncthreads();  // single barrier per step

    cur = nxt;
    nxt = pre;
  }

  if (owner) {
    hstate[b * Hh + u] = hreg;
    cstate[b * Hh + u] = creg;
    h32[sub][u] = hreg;
  }
  __syncthreads();

  // Final FC fused into the last chunk (2 batches x 4 outputs per block)
  if (t0 + TC == Tt && tid < 8) {
    int s2 = tid >> 2, g = tid & 3;
    int bb = blockIdx.x * 2 + s2;
    float s = fc_b[g];
    for (int jj = 0; jj < Hh; ++jj)
      s = fmaf(h32[s2][jj], fc_w[g * Hh + jj], s);
    out[bb * 4 + g] = s;
  }
}

// ---------------------------------------------------------------------------
template <int TC>
static void run_chunks(const float* x, const float* gamma, const float* beta,
                       const float* rmean, const float* rvar,
                       const float* W_ih, const float* W_hh,
                       const float* b_ih, const float* b_hh,
                       const float* fc_w, const float* fc_b, float* out,
                       void* d_ws, hipStream_t stream) {
  char* ws = reinterpret_cast<char*>(d_ws);
  float* xwp  = reinterpret_cast<float*>(ws);
  size_t off  = (size_t)Bb * TC * G * 4;
  float* hst  = reinterpret_cast<float*>(ws + off);  off += (size_t)Bb * Hh * 4;
  float* cst  = reinterpret_cast<float*>(ws + off);  off += (size_t)Bb * Hh * 4;
  float* bia  = reinterpret_cast<float*>(ws + off);  off += 512 * 4;
  off = (off + 15) & ~(size_t)15;
  _Float16* Wp = reinterpret_cast<_Float16*>(ws + off);

  k0_prep<<<dim3(1), dim3(512), 0, stream>>>(gamma, beta, rmean, rvar, W_ih,
                                             b_ih, b_hh, bia, Wp);
  for (int t0 = 0; t0 < Tt; t0 += TC) {
    k1_mfma<TC><<<dim3(Bb * TC / 64), dim3(512), 0, stream>>>(x, Wp, bia, xwp,
                                                              t0);
    k2_lstm<TC><<<dim3(Bb / 2), dim3(512), 0, stream>>>(xwp, W_hh, hst, cst,
                                                        fc_w, fc_b, out, t0);
  }
}

extern "C" void kernel_launch(void* const* d_in, const int* in_sizes, int n_in,
                              void* d_out, int out_size, void* d_ws,
                              size_t ws_size, hipStream_t stream) {
  const float* x     = (const float*)d_in[0];
  const float* gamma = (const float*)d_in[1];
  const float* beta  = (const float*)d_in[2];
  const float* rmean = (const float*)d_in[3];
  const float* rvar  = (const float*)d_in[4];
  const float* W_ih  = (const float*)d_in[5];
  const float* W_hh  = (const float*)d_in[6];
  const float* b_ih  = (const float*)d_in[7];
  const float* b_hh  = (const float*)d_in[8];
  const float* fc_w  = (const float*)d_in[9];
  const float* fc_b  = (const float*)d_in[10];
  float* out = (float*)d_out;

  auto need = [](int tc) {
    return (size_t)Bb * tc * G * 4 + 2 * (size_t)Bb * Hh * 4 + 512 * 4 + 16 +
           (size_t)512 * 96 * 2;
  };

  if (ws_size >= need(500)) {
    run_chunks<500>(x, gamma, beta, rmean, rvar, W_ih, W_hh, b_ih, b_hh, fc_w,
                    fc_b, out, d_ws, stream);
  } else if (ws_size >= need(250)) {
    run_chunks<250>(x, gamma, beta, rmean, rvar, W_ih, W_hh, b_ih, b_hh, fc_w,
                    fc_b, out, d_ws, stream);
  } else if (ws_size >= need(125)) {
    run_chunks<125>(x, gamma, beta, rmean, rvar, W_ih, W_hh, b_ih, b_hh, fc_w,
                    fc_b, out, d_ws, stream);
  } else if (ws_size >= need(50)) {
    run_chunks<50>(x, gamma, beta, rmean, rvar, W_ih, W_hh, b_ih, b_hh, fc_w,
                   fc_b, out, d_ws, stream);
  } else {
    run_chunks<10>(x, gamma, beta, rmean, rvar, W_ih, W_hh, b_ih, b_hh, fc_w,
                   fc_b, out, d_ws, stream);
  }
}

// Round 8
// 841.026 us; speedup vs baseline: 1.5284x; 1.5284x over previous
//
#include <hip/hip_runtime.h>
#include <cstdint>

// Problem constants
constexpr int Cc = 95;    // input channels
constexpr int Hh = 128;   // hidden
constexpr int G  = 512;   // 4*H gates
constexpr int Bb = 256;   // batch
constexpr int Tt = 1000;  // timesteps
#define EPSBN 1e-5f

typedef _Float16 half8  __attribute__((ext_vector_type(8)));
typedef float floatx4 __attribute__((ext_vector_type(4)));
typedef float float4u __attribute__((ext_vector_type(4), aligned(4)));
typedef float float2u __attribute__((ext_vector_type(2), aligned(4)));

__device__ __forceinline__ unsigned pku(float a, float b) {
  return __builtin_bit_cast(unsigned, __builtin_amdgcn_cvt_pkrtz(a, b));
}
__device__ __forceinline__ float fsigm(float y) {
  y = fminf(30.f, fmaxf(-30.f, y));
  float e = __expf(-y);
  return __fdividef(1.f, 1.f + e);
}
__device__ __forceinline__ float ftanh2(float x) {  // tanh via exp(2x)
  float y = fminf(30.f, fmaxf(-30.f, 2.f * x));
  float e = __expf(y);
  return __fdividef(e - 1.f, e + 1.f);
}

// ---------------------------------------------------------------------------
// K0: fold BN into W_ih -> Wp f16 [512][96] (k=95 padded 0),
// bias'[g] = b_ih+b_hh + sum_c sft_c * W_ih[g][c].
// ---------------------------------------------------------------------------
__global__ __launch_bounds__(512)
void k0_prep(const float* __restrict__ gamma, const float* __restrict__ beta,
             const float* __restrict__ rmean, const float* __restrict__ rvar,
             const float* __restrict__ W_ih, const float* __restrict__ b_ih,
             const float* __restrict__ b_hh, float* __restrict__ biasp,
             _Float16* __restrict__ Wp) {
  __shared__ float scl[Cc], sft[Cc];
  const int t = threadIdx.x;
  if (t < Cc) {
    float s = gamma[t] * rsqrtf(rvar[t] + EPSBN);
    scl[t] = s;
    sft[t] = beta[t] - rmean[t] * s;
  }
  __syncthreads();
  float acc = b_ih[t] + b_hh[t];
  const float* wr = W_ih + (size_t)t * Cc;
  for (int c = 0; c < Cc; ++c) {
    float w = wr[c];
    acc = fmaf(sft[c], w, acc);
    Wp[t * 96 + c] = (_Float16)(w * scl[c]);
  }
  Wp[t * 96 + 95] = (_Float16)0.f;
  biasp[t] = acc;
}

// ---------------------------------------------------------------------------
// K1: xw[m][g] = x_f16 . Wp^T + bias' via mfma_f32_16x16x32_f16.
// kk-outer / nt-inner: adjacent MFMAs from independent chains.
// Contiguous stores (lane l15 -> consecutive gate col).
// ---------------------------------------------------------------------------
template <int TC>
__global__ __launch_bounds__(512)
void k1_mfma(const float* __restrict__ x, const _Float16* __restrict__ Wp,
             const float* __restrict__ biasp, float* __restrict__ xw, int t0) {
  const int tid = threadIdx.x;
  const int wave = tid >> 6, lane = tid & 63;
  const int wm = wave >> 2, wn = wave & 3;
  const int row0 = blockIdx.x * 64 + wm * 32;
  const int nb0 = wn * 128;
  const int l15 = lane & 15, lg = lane >> 4;

  uint4 afr[2][3];
#pragma unroll
  for (int mt = 0; mt < 2; ++mt) {
    int m = row0 + mt * 16 + l15;
    int b = m / TC, tl = m - b * TC;
    const float* xr = x + ((size_t)b * Tt + t0 + tl) * Cc;
#pragma unroll
    for (int kk = 0; kk < 3; ++kk) {
      int k = kk * 32 + lg * 8;
      float4u p0 = *reinterpret_cast<const float4u*>(xr + k);
      float e4, e5, e6, e7;
      if (k == 88) {
        float2u q = *reinterpret_cast<const float2u*>(xr + 92);
        e4 = q[0]; e5 = q[1]; e6 = xr[94]; e7 = 0.f;
      } else {
        float4u p1 = *reinterpret_cast<const float4u*>(xr + k + 4);
        e4 = p1[0]; e5 = p1[1]; e6 = p1[2]; e7 = p1[3];
      }
      afr[mt][kk] = make_uint4(pku(p0[0], p0[1]), pku(p0[2], p0[3]),
                               pku(e4, e5), pku(e6, e7));
    }
  }

  floatx4 acc[2][8] = {};
#pragma unroll
  for (int kk = 0; kk < 3; ++kk)
#pragma unroll
    for (int nt = 0; nt < 8; ++nt) {
      const _Float16* wrow = Wp + (size_t)(nb0 + nt * 16 + l15) * 96 + lg * 8;
      uint4 bfr = *reinterpret_cast<const uint4*>(wrow + kk * 32);
      half8 bv = __builtin_bit_cast(half8, bfr);
      acc[0][nt] = __builtin_amdgcn_mfma_f32_16x16x32_f16(
          __builtin_bit_cast(half8, afr[0][kk]), bv, acc[0][nt], 0, 0, 0);
      acc[1][nt] = __builtin_amdgcn_mfma_f32_16x16x32_f16(
          __builtin_bit_cast(half8, afr[1][kk]), bv, acc[1][nt], 0, 0, 0);
    }

#pragma unroll
  for (int nt = 0; nt < 8; ++nt) {
    int n = nb0 + nt * 16 + l15;
    float bias = biasp[n];
#pragma unroll
    for (int mt = 0; mt < 2; ++mt) {
      int rbase = row0 + mt * 16 + lg * 4;
#pragma unroll
      for (int r = 0; r < 4; ++r)
        xw[(size_t)(rbase + r) * G + n] = acc[mt][nt][r] + bias;
    }
  }
}

// ---------------------------------------------------------------------------
// K2: LSTM recurrence via MFMA. 256 blocks (1 batch/block, all CUs) x 256 thr.
// Wave w owns units [32w,32w+32): A-frags = W_hh rows, f16, 128 VGPR.
// Per step: 4x ds_read_b128 (h broadcast) -> 32 MFMA (kc-outer: independent
// adjacent) -> in-register gate extraction -> activations -> h f16 -> LDS.
// Raw s_barrier + lgkmcnt-only wait (NO vmcnt drain -> 4-deep xw prefetch
// survives the barrier). Prefetch ring statically indexed via macro unroll.
// ---------------------------------------------------------------------------
template <int TC>
__global__ __launch_bounds__(256, 1)
void k2_lstm(const float* __restrict__ xw, const float* __restrict__ W_hh,
             float* __restrict__ hstate, float* __restrict__ cstate,
             const float* __restrict__ fc_w, const float* __restrict__ fc_b,
             float* __restrict__ out, int t0) {
  __shared__ __align__(16) _Float16 h2[2][Hh];
  __shared__ float h32[Hh];

  const int b = blockIdx.x;
  const int tid = threadIdx.x;
  const int w = tid >> 6, lane = tid & 63;
  const int l15 = lane & 15, lg = lane >> 4;
  const int hh = l15 & 1, rr = (l15 >> 1) & 3;   // l15>=8 duplicates
  const int u = 32 * w + 16 * hh + 4 * lg + rr;  // unit this lane updates
  const bool owner = (l15 < 8);

  // A-fragments: W_hh rows (f16) 8 tiles x 4 k-chunks -> 128 VGPRs
  uint4 afr[8][4];
#pragma unroll
  for (int q = 0; q < 4; ++q)
#pragma unroll
    for (int h2i = 0; h2i < 2; ++h2i) {
      const float* wr =
          W_hh + (size_t)(q * 128 + 32 * w + 16 * h2i + l15) * Hh + 8 * lg;
#pragma unroll
      for (int kc = 0; kc < 4; ++kc) {
        float4u p0 = *reinterpret_cast<const float4u*>(wr + 32 * kc);
        float4u p1 = *reinterpret_cast<const float4u*>(wr + 32 * kc + 4);
        afr[2 * q + h2i][kc] = make_uint4(pku(p0[0], p0[1]), pku(p0[2], p0[3]),
                                          pku(p1[0], p1[1]), pku(p1[2], p1[3]));
      }
    }

  float creg = 0.f, hreg = 0.f;
  if (t0 == 0) {
    if (owner) h2[0][u] = (_Float16)0.f;
  } else {
    creg = cstate[b * Hh + u];
    hreg = hstate[b * Hh + u];
    if (owner) h2[0][u] = (_Float16)hreg;
  }
  __syncthreads();

  const float* xwb = xw + (size_t)b * TC * G;

  // 4-deep prefetch ring, statically indexed (macro slots)
  float pi[4], pf[4], pg[4], po[4];
#pragma unroll
  for (int i = 0; i < 4; ++i) {
    if (i < TC) {
      const float* xp = xwb + (size_t)i * G;
      pi[i] = xp[0 * 128 + u]; pf[i] = xp[1 * 128 + u];
      pg[i] = xp[2 * 128 + u]; po[i] = xp[3 * 128 + u];
    } else {
      pi[i] = pf[i] = pg[i] = po[i] = 0.f;
    }
  }

#define K2_STEP(TL, SL)                                                        \
  {                                                                            \
    const int tl_ = (TL);                                                      \
    const int rb_ = tl_ & 1;                                                   \
    float ci = pi[SL], cf = pf[SL], cg = pg[SL], co = po[SL];                  \
    if (tl_ + 4 < TC) {                                                        \
      const float* xp_ = xwb + (size_t)(tl_ + 4) * G;                          \
      pi[SL] = xp_[0 * 128 + u]; pf[SL] = xp_[1 * 128 + u];                    \
      pg[SL] = xp_[2 * 128 + u]; po[SL] = xp_[3 * 128 + u];                    \
    }                                                                          \
    uint4 bfr[4];                                                              \
    _Pragma("unroll") for (int kc = 0; kc < 4; ++kc)                           \
        bfr[kc] = *reinterpret_cast<const uint4*>(&h2[rb_][32 * kc + 8 * lg]); \
    floatx4 acc[8] = {};                                                       \
    _Pragma("unroll") for (int kc = 0; kc < 4; ++kc)                           \
        _Pragma("unroll") for (int t_ = 0; t_ < 8; ++t_)                       \
            acc[t_] = __builtin_amdgcn_mfma_f32_16x16x32_f16(                  \
                __builtin_bit_cast(half8, afr[t_][kc]),                        \
                __builtin_bit_cast(half8, bfr[kc]), acc[t_], 0, 0, 0);         \
    float gq[4];                                                               \
    _Pragma("unroll") for (int q_ = 0; q_ < 4; ++q_) {                         \
      float e0 = hh ? acc[2 * q_ + 1][0] : acc[2 * q_][0];                     \
      float e1 = hh ? acc[2 * q_ + 1][1] : acc[2 * q_][1];                     \
      float e2 = hh ? acc[2 * q_ + 1][2] : acc[2 * q_][2];                     \
      float e3 = hh ? acc[2 * q_ + 1][3] : acc[2 * q_][3];                     \
      float lo = (rr & 1) ? e1 : e0;                                           \
      float hi = (rr & 1) ? e3 : e2;                                           \
      gq[q_] = (rr & 2) ? hi : lo;                                             \
    }                                                                          \
    float i_ = fsigm(gq[0] + ci);                                              \
    float f_ = fsigm(gq[1] + cf);                                              \
    float g_ = ftanh2(gq[2] + cg);                                             \
    float o_ = fsigm(gq[3] + co);                                              \
    creg = fmaf(f_, creg, i_ * g_);                                            \
    hreg = o_ * ftanh2(creg);                                                  \
    if (owner) h2[rb_ ^ 1][u] = (_Float16)hreg;                                \
    asm volatile("s_waitcnt lgkmcnt(0)" ::: "memory");                         \
    __builtin_amdgcn_s_barrier();                                              \
    __builtin_amdgcn_sched_barrier(0);                                         \
  }

  int tl = 0;
  for (; tl + 4 <= TC; tl += 4) {
    K2_STEP(tl + 0, 0)
    K2_STEP(tl + 1, 1)
    K2_STEP(tl + 2, 2)
    K2_STEP(tl + 3, 3)
  }
  if constexpr ((TC & 3) >= 1) K2_STEP(TC & ~3, 0)
  if constexpr ((TC & 3) >= 2) K2_STEP((TC & ~3) + 1, 1)
  if constexpr ((TC & 3) >= 3) K2_STEP((TC & ~3) + 2, 2)
#undef K2_STEP

  if (owner) {
    hstate[b * Hh + u] = hreg;
    cstate[b * Hh + u] = creg;
    h32[u] = hreg;
  }
  __syncthreads();

  if (t0 + TC == Tt && tid < 4) {
    float s = fc_b[tid];
    for (int jj = 0; jj < Hh; ++jj) s = fmaf(h32[jj], fc_w[tid * Hh + jj], s);
    out[b * 4 + tid] = s;
  }
}

// ---------------------------------------------------------------------------
template <int TC>
static void run_chunks(const float* x, const float* gamma, const float* beta,
                       const float* rmean, const float* rvar,
                       const float* W_ih, const float* W_hh,
                       const float* b_ih, const float* b_hh,
                       const float* fc_w, const float* fc_b, float* out,
                       void* d_ws, hipStream_t stream) {
  char* ws = reinterpret_cast<char*>(d_ws);
  float* xwp  = reinterpret_cast<float*>(ws);
  size_t off  = (size_t)Bb * TC * G * 4;
  float* hst  = reinterpret_cast<float*>(ws + off);  off += (size_t)Bb * Hh * 4;
  float* cst  = reinterpret_cast<float*>(ws + off);  off += (size_t)Bb * Hh * 4;
  float* bia  = reinterpret_cast<float*>(ws + off);  off += 512 * 4;
  off = (off + 15) & ~(size_t)15;
  _Float16* Wp = reinterpret_cast<_Float16*>(ws + off);

  k0_prep<<<dim3(1), dim3(512), 0, stream>>>(gamma, beta, rmean, rvar, W_ih,
                                             b_ih, b_hh, bia, Wp);
  for (int t0 = 0; t0 < Tt; t0 += TC) {
    k1_mfma<TC><<<dim3(Bb * TC / 64), dim3(512), 0, stream>>>(x, Wp, bia, xwp,
                                                              t0);
    k2_lstm<TC><<<dim3(Bb), dim3(256), 0, stream>>>(xwp, W_hh, hst, cst, fc_w,
                                                    fc_b, out, t0);
  }
}

extern "C" void kernel_launch(void* const* d_in, const int* in_sizes, int n_in,
                              void* d_out, int out_size, void* d_ws,
                              size_t ws_size, hipStream_t stream) {
  const float* x     = (const float*)d_in[0];
  const float* gamma = (const float*)d_in[1];
  const float* beta  = (const float*)d_in[2];
  const float* rmean = (const float*)d_in[3];
  const float* rvar  = (const float*)d_in[4];
  const float* W_ih  = (const float*)d_in[5];
  const float* W_hh  = (const float*)d_in[6];
  const float* b_ih  = (const float*)d_in[7];
  const float* b_hh  = (const float*)d_in[8];
  const float* fc_w  = (const float*)d_in[9];
  const float* fc_b  = (const float*)d_in[10];
  float* out = (float*)d_out;

  auto need = [](int tc) {
    return (size_t)Bb * tc * G * 4 + 2 * (size_t)Bb * Hh * 4 + 512 * 4 + 16 +
           (size_t)512 * 96 * 2;
  };

  if (ws_size >= need(250)) {
    run_chunks<250>(x, gamma, beta, rmean, rvar, W_ih, W_hh, b_ih, b_hh, fc_w,
                    fc_b, out, d_ws, stream);
  } else if (ws_size >= need(125)) {
    run_chunks<125>(x, gamma, beta, rmean, rvar, W_ih, W_hh, b_ih, b_hh, fc_w,
                    fc_b, out, d_ws, stream);
  } else if (ws_size >= need(50)) {
    run_chunks<50>(x, gamma, beta, rmean, rvar, W_ih, W_hh, b_ih, b_hh, fc_w,
                   fc_b, out, d_ws, stream);
  } else {
    run_chunks<10>(x, gamma, beta, rmean, rvar, W_ih, W_hh, b_ih, b_hh, fc_w,
                   fc_b, out, d_ws, stream);
  }
}